// Round 3
// baseline (1201.735 us; speedup 1.0000x reference)
//
#include <hip/hip_runtime.h>
#include <hip/hip_bf16.h>
#include <stdint.h>

// Problem constants (B=2, NV=25000, C=32, NR=3, ND=16, F=64)
#define NVERT 25000      // vertices per batch
#define NPAIR 25000      // total vertex-pairs (B*NV/2)
#define NGROUP 6250      // NPAIR/4: groups of 4 pairs (8 vertices) per wave-iter

typedef __bf16  bf16x8 __attribute__((ext_vector_type(8)));
typedef float   f32x16 __attribute__((ext_vector_type(16)));

#define NCHUNK 98                       // 96 conv chunks (r,ch,j) + 2 center chunks
#define BPACK_HALF_USHORT (NCHUNK*512)  // ushorts per f-half fragment pack
#define LDS_TOT (NCHUNK*1024)           // 100352 B: B-fragments only; 1 block/CU, 8 waves

__device__ __forceinline__ unsigned short f2bf(float f) {
  unsigned int u = __float_as_uint(f);
  u += 0x7FFFu + ((u >> 16) & 1u);   // round-to-nearest-even
  return (unsigned short)(u >> 16);
}

// lane-rotate within 16-lane rows: dst[i] = src[(i+1)&15]  (row_ror:15)
__device__ __forceinline__ bf16x8 rot16(bf16x8 x) {
  union { bf16x8 v; int i[4]; } u;
  u.v = x;
#pragma unroll
  for (int k = 0; k < 4; ++k)
    u.i[k] = __builtin_amdgcn_update_dpp(0, u.i[k], 0x12F, 0xF, 0xF, true);
  return u.v;
}

// 8 f32 -> 8 bf16 (rne), in-register
__device__ __forceinline__ bf16x8 pack8(float4 v0, float4 v1) {
  union { bf16x8 v; unsigned u[4]; } r;
  r.u[0] = (unsigned)f2bf(v0.x) | ((unsigned)f2bf(v0.y) << 16);
  r.u[1] = (unsigned)f2bf(v0.z) | ((unsigned)f2bf(v0.w) << 16);
  r.u[2] = (unsigned)f2bf(v1.x) | ((unsigned)f2bf(v1.y) << 16);
  r.u[3] = (unsigned)f2bf(v1.z) | ((unsigned)f2bf(v1.w) << 16);
  return r.v;
}

// Pack kernel (3,16,32,64) + center_kernel (32,64) into MFMA B-fragment order, bf16.
// Layout: bpack[fh(2)][kc(98)][lane(64)][i(8)] ushort.
// kc = (r*2+ch)*16 + j for conv; kc = 96+ch for center. B[k][n]: n=lane&31, k=8*(lane>>5)+i, c=ch*16+k.
__global__ __launch_bounds__(256) void prepack_kernel(
    const float* __restrict__ kern, const float* __restrict__ ckern,
    unsigned short* __restrict__ bpack)
{
  int tid = blockIdx.x*256 + threadIdx.x;
  if (tid >= 2*BPACK_HALF_USHORT) return;
  int fh  = tid / BPACK_HALF_USHORT;
  int rem = tid - fh*BPACK_HALF_USHORT;
  int kc  = rem >> 9;
  int e   = rem & 511;
  int l   = e >> 3, i = e & 7;
  int f   = fh*32 + (l & 31);
  int kk  = ((l >> 5) << 3) + i;
  float v;
  if (kc < 96) {
    int r = kc >> 5, ch = (kc >> 4) & 1, j = kc & 15;
    int c = ch*16 + kk;
    v = kern[((r*16 + j)*32 + c)*64 + f];
  } else {
    int c = (kc - 96)*16 + kk;
    v = ckern[c*64 + f];
  }
  bpack[tid] = f2bf(v);
}

__global__ __launch_bounds__(512, 2) void conv_kernel(
    const float* __restrict__ y,
    const int*   __restrict__ em,     // exp_map int pairs (b,v), flat (u*48 + r*16+dd)
    const float* __restrict__ bias,
    const unsigned short* __restrict__ bpack,
    float* __restrict__ out)
{
  extern __shared__ __align__(16) char smem[];
  const int fh  = blockIdx.x & 1;     // which 32-wide f half
  const int bl  = blockIdx.x >> 1;    // 0..127
  const int tid = threadIdx.x;
  const int w   = tid >> 6;           // wave 0..7
  const int l   = tid & 63;

  // ---- stage this f-half's B fragments into LDS (once per block) ----
  {
    const uint4* src = (const uint4*)(bpack + (size_t)fh * BPACK_HALF_USHORT);
    uint4* dst = (uint4*)smem;
    for (int i = tid; i < LDS_TOT/16; i += 512) dst[i] = src[i];
  }
  __syncthreads();
  // No barriers after this; 8 waves drift independently feeding the MFMA pipes.

  const int q  = (l >> 4) & 1;        // A-operand: which vertex of the pair (m>>4)
  const int d  = l & 15;              // A-operand: direction (m&15)
  const int hi = l >> 5;              // A/B operand: k-half selector
  const float biasv = bias[fh*32 + (l & 31)];
  const char* bbase = smem + (size_t)l * 16;   // conflict-free: wave spans contiguous 1KB
  const int2* em2 = (const int2*)em;
  const int gw = bl*8 + w;            // global wave id within f-half, 0..1023

  for (int g = gw; g < NGROUP; g += 1024) {
    const int vpb = g * 4;            // first of 4 pairs (8 vertices) this iter

    // ---- per-lane em gather: lane owns (vertex q, direction d) of each pair ----
    int2 e[4][3];
#pragma unroll
    for (int p = 0; p < 4; ++p) {
      const int u = (vpb + p)*2 + q;
#pragma unroll
      for (int r = 0; r < 3; ++r) e[p][r] = em2[u*48 + r*16 + d];
    }

    f32x16 acc[4];
#pragma unroll
    for (int p = 0; p < 4; ++p)
#pragma unroll
      for (int k = 0; k < 16; ++k) acc[p][k] = 0.f;

    // ---- conv: 6 k-chunk groups x 16 j-rotations; A gathered to regs, B from LDS ----
#pragma unroll
    for (int r = 0; r < 3; ++r) {
#pragma unroll
      for (int ch = 0; ch < 2; ++ch) {
        bf16x8 a[4];
#pragma unroll
        for (int p = 0; p < 4; ++p) {
          const float* yr = y + ((size_t)e[p][r].x*NVERT + (size_t)e[p][r].y)*32
                              + ch*16 + hi*8;
          a[p] = pack8(*(const float4*)yr, *(const float4*)(yr + 4));
        }
        const char* bp = bbase + (size_t)((r*2 + ch)*16) * 1024;
#pragma unroll
        for (int j = 0; j < 16; ++j) {
          const bf16x8 b = *(const bf16x8*)(bp + j*1024);
#pragma unroll
          for (int p = 0; p < 4; ++p)
            acc[p] = __builtin_amdgcn_mfma_f32_32x32x16_bf16(a[p], b, acc[p], 0, 0, 0);
          if (j < 15) {
#pragma unroll
            for (int p = 0; p < 4; ++p) a[p] = rot16(a[p]);
          }
        }
      }
    }

    // ---- center term: 2 chunks, A-row = y[u] broadcast across d ----
#pragma unroll
    for (int ch = 0; ch < 2; ++ch) {
      const bf16x8 b = *(const bf16x8*)(bbase + (size_t)(96 + ch)*1024);
#pragma unroll
      for (int p = 0; p < 4; ++p) {
        const int u = (vpb + p)*2 + q;
        const float* yr = y + (size_t)u*32 + ch*16 + hi*8;
        bf16x8 a = pack8(*(const float4*)yr, *(const float4*)(yr + 4));
        acc[p] = __builtin_amdgcn_mfma_f32_32x32x16_bf16(a, b, acc[p], 0, 0, 0);
      }
    }

    // ---- epilogue: max over d, +bias, relu, store ----
    // C/D layout (m74/m101): n = lane&31, m = (reg&3)+8*(reg>>2)+4*(lane>>5).
    // regs 0..7 -> vertex 0 rows, regs 8..15 -> vertex 1; lane^32 holds the other 8 d's.
#pragma unroll
    for (int p = 0; p < 4; ++p) {
      float m0 = acc[p][0], m1 = acc[p][8];
#pragma unroll
      for (int k = 1; k < 8; ++k) { m0 = fmaxf(m0, acc[p][k]); m1 = fmaxf(m1, acc[p][8+k]); }
      m0 = fmaxf(m0, __shfl_xor(m0, 32, 64));
      m1 = fmaxf(m1, __shfl_xor(m1, 32, 64));
      float v = (hi ? m1 : m0) + biasv;
      out[(size_t)((vpb + p)*2 + hi)*64 + fh*32 + (l & 31)] = fmaxf(v, 0.f);
    }
  }
}

extern "C" void kernel_launch(void* const* d_in, const int* in_sizes, int n_in,
                              void* d_out, int out_size, void* d_ws, size_t ws_size,
                              hipStream_t stream) {
  const float* y     = (const float*)d_in[0];
  const int*   em    = (const int*)  d_in[1];
  const float* kern  = (const float*)d_in[2];
  const float* ckern = (const float*)d_in[3];
  const float* bias  = (const float*)d_in[4];
  float* out = (float*)d_out;
  unsigned short* bpack = (unsigned short*)d_ws;   // 200704 bytes used

  // opt in to >64KB dynamic LDS (host-side, graph-capture safe — verified round 1)
  hipFuncSetAttribute(reinterpret_cast<const void*>(conv_kernel),
                      hipFuncAttributeMaxDynamicSharedMemorySize, LDS_TOT);

  prepack_kernel<<<(2*BPACK_HALF_USHORT + 255)/256, 256, 0, stream>>>(kern, ckern, bpack);
  conv_kernel<<<256, 512, LDS_TOT, stream>>>(y, em, bias, bpack, out);
}

// Round 4
// 239.297 us; speedup vs baseline: 5.0219x; 5.0219x over previous
//
#include <hip/hip_runtime.h>
#include <stdint.h>

// Problem constants (B=2, NV=25000, C=32, NR=3, ND=16, F=64)
#define NVERT 25000      // vertices per batch
#define NPAIR 25000      // total vertex-pairs (B*NV/2)
#define NGRP  12500      // pair-groups of 2 pairs (4 vertices) per wave-iter

typedef __bf16  bf16x8 __attribute__((ext_vector_type(8)));
typedef float   f32x16 __attribute__((ext_vector_type(16)));

#define NCHUNK 98                       // 96 conv chunks (r,ch,j) + 2 center chunks
#define BPACK_HALF_USHORT (NCHUNK*512)  // ushorts per f-half fragment pack
#define LDS_B   (NCHUNK*1024)           // 100352 B of B-fragments in LDS
#define ROWB    80                      // patch row stride (32 bf16 + 16B pad -> 2-way banks, free)
#define VSTRIDE (49*ROWB)               // per-vertex patch (48 rows + 1 center row) = 3920
#define WSTRIDE (4*VSTRIDE)             // per wave: 4 vertices (2 pairs) = 15680
#define LDS_TOT (LDS_B + 4*WSTRIDE)     // 163072 <= 163840

__device__ __forceinline__ unsigned short f2bf(float f) {
  unsigned int u = __float_as_uint(f);
  u += 0x7FFFu + ((u >> 16) & 1u);   // round-to-nearest-even
  return (unsigned short)(u >> 16);
}

__device__ __forceinline__ uint2 pack4(float4 v) {
  uint2 r;
  r.x = (unsigned)f2bf(v.x) | ((unsigned)f2bf(v.y) << 16);
  r.y = (unsigned)f2bf(v.z) | ((unsigned)f2bf(v.w) << 16);
  return r;
}

// lane-rotate within 16-lane rows: dst[i] = src[(i+1)&15]  (row_ror:15)
__device__ __forceinline__ bf16x8 rot16(bf16x8 x) {
  union { bf16x8 v; int i[4]; } u;
  u.v = x;
#pragma unroll
  for (int k = 0; k < 4; ++k)
    u.i[k] = __builtin_amdgcn_update_dpp(0, u.i[k], 0x12F, 0xF, 0xF, true);
  return u.v;
}

// Pack kernel (3,16,32,64) + center_kernel (32,64) into MFMA B-fragment order, bf16.
// Layout: bpack[fh(2)][kc(98)][lane(64)][i(8)] ushort.
// kc = (r*2+ch)*16 + j for conv; kc = 96+ch for center. B[k][n]: n=lane&31, k=8*(lane>>5)+i, c=ch*16+k.
__global__ __launch_bounds__(256) void prepack_kernel(
    const float* __restrict__ kern, const float* __restrict__ ckern,
    unsigned short* __restrict__ bpack)
{
  int tid = blockIdx.x*256 + threadIdx.x;
  if (tid >= 2*BPACK_HALF_USHORT) return;
  int fh  = tid / BPACK_HALF_USHORT;
  int rem = tid - fh*BPACK_HALF_USHORT;
  int kc  = rem >> 9;
  int e   = rem & 511;
  int l   = e >> 3, i = e & 7;
  int f   = fh*32 + (l & 31);
  int kk  = ((l >> 5) << 3) + i;
  float v;
  if (kc < 96) {
    int r = kc >> 5, ch = (kc >> 4) & 1, j = kc & 15;
    int c = ch*16 + kk;
    v = kern[((r*16 + j)*32 + c)*64 + f];
  } else {
    int c = (kc - 96)*16 + kk;
    v = ckern[c*64 + f];
  }
  bpack[tid] = f2bf(v);
}

// One (r,ch) chunk-group: A from LDS (rotated in-register over j), B 2-deep reg-prefetched.
#define CHUNK_GROUP(rr, cc)                                                    \
  {                                                                            \
    const char* ap = pbase + q*VSTRIDE + ((rr)*16 + d)*ROWB + (cc)*32 + hi*16; \
    bf16x8 a0 = *(const bf16x8*)ap;                                            \
    bf16x8 a1 = *(const bf16x8*)(ap + 2*VSTRIDE);                              \
    const char* bp = bbase + (size_t)(((rr)*2 + (cc))*16) * 1024;              \
    bf16x8 b0 = *(const bf16x8*)bp;                                            \
    bf16x8 b1 = *(const bf16x8*)(bp + 1024);                                   \
    _Pragma("unroll")                                                          \
    for (int j = 0; j < 16; ++j) {                                             \
      const bf16x8 b = b0;                                                     \
      b0 = b1;                                                                 \
      if (j < 14) b1 = *(const bf16x8*)(bp + (size_t)(j+2)*1024);              \
      acc0 = __builtin_amdgcn_mfma_f32_32x32x16_bf16(a0, b, acc0, 0, 0, 0);    \
      acc1 = __builtin_amdgcn_mfma_f32_32x32x16_bf16(a1, b, acc1, 0, 0, 0);    \
      if (j < 15) { a0 = rot16(a0); a1 = rot16(a1); }                          \
    }                                                                          \
  }

__global__ __launch_bounds__(256, 1) void conv_kernel(
    const float* __restrict__ y,
    const int*   __restrict__ em,     // exp_map int pairs (b,v), flat (u*48 + r*16+dd)
    const float* __restrict__ bias,
    const unsigned short* __restrict__ bpack,
    float* __restrict__ out)
{
  extern __shared__ __align__(16) char smem[];
  const int fh  = blockIdx.x & 1;     // which 32-wide f half
  const int bl  = blockIdx.x >> 1;    // 0..127
  const int tid = threadIdx.x;
  const int w   = tid >> 6;           // wave 0..3
  const int l   = tid & 63;

  // ---- stage this f-half's B fragments into LDS (once per block) ----
  {
    const uint4* src = (const uint4*)(bpack + (size_t)fh * BPACK_HALF_USHORT);
    uint4* dst = (uint4*)smem;
    for (int idx = tid; idx < LDS_B/16; idx += 256) dst[idx] = src[idx];
  }
  __syncthreads();
  // No barriers after this; per-wave DS ordering protects the private patch buffer.

  char* pbase = smem + LDS_B + w * WSTRIDE;
  const char* bbase = smem + (size_t)l * 16;    // canonical fragment read: 0 conflicts (R3 PMC)
  const float biasv = bias[fh*32 + (l & 31)];
  const int gw = bl*4 + w;            // global wave id within f-half, 0..511
  const int q  = (l >> 4) & 1;        // A-operand: which vertex of the pair (m>>4)
  const int d  = l & 15;              // A-operand: direction (m&15)
  const int hi = l >> 5;              // A/B operand: k-half selector
  const int2* em2 = (const int2*)em;
  // staging lane roles: row-slot = l>>3 (8 rows/step), c-quarter = l&7
  const int rsl = l >> 3, cp = l & 7;

  int g = gw;
  bool valid = (g < NGRP);

  // ---- prologue: stage group g fully (latency exposed once) ----
  if (valid) {
    int2 e0[24];
#pragma unroll
    for (int it = 0; it < 24; ++it)
      e0[it] = em2[(g*4 + (it & 3))*48 + (it >> 2)*8 + rsl];
    float4 yv0[25];
#pragma unroll
    for (int it = 0; it < 24; ++it)
      yv0[it] = *(const float4*)(y + ((size_t)e0[it].x*NVERT + (size_t)e0[it].y)*32 + cp*4);
    yv0[24] = *(const float4*)(y + (size_t)(g*4 + (rsl & 3))*32 + cp*4);
#pragma unroll
    for (int it = 0; it < 24; ++it)
      *(uint2*)(pbase + (it & 3)*VSTRIDE + ((it >> 2)*8 + rsl)*ROWB + cp*8) = pack4(yv0[it]);
    if (l < 32)
      *(uint2*)(pbase + rsl*VSTRIDE + 48*ROWB + cp*8) = pack4(yv0[24]);
  }

  for (int t = 0; t < 25; ++t) {
    if (!valid) break;
    const int gn = g + 512;
    const bool vnext = (gn < NGRP);

    // ---- Phase A: issue next group's em loads (latency hidden by r=0 compute) ----
    int2 e[24];
    if (vnext) {
#pragma unroll
      for (int it = 0; it < 24; ++it)
        e[it] = em2[(gn*4 + (it & 3))*48 + (it >> 2)*8 + rsl];
    }

    f32x16 acc0, acc1;
#pragma unroll
    for (int k = 0; k < 16; ++k) { acc0[k] = 0.f; acc1[k] = 0.f; }

    // ---- Phase B: r=0 (2048 cyc of MFMA pipe covers em latency) ----
    CHUNK_GROUP(0, 0)
    CHUNK_GROUP(0, 1)

    // ---- Phase C: issue next group's y gathers (latency hidden by r=1,2) ----
    float4 yv[25];
    if (vnext) {
#pragma unroll
      for (int it = 0; it < 24; ++it)
        yv[it] = *(const float4*)(y + ((size_t)e[it].x*NVERT + (size_t)e[it].y)*32 + cp*4);
      yv[24] = *(const float4*)(y + (size_t)(gn*4 + (rsl & 3))*32 + cp*4);
    }

    // ---- Phase D: r=1, r=2, center ----
    CHUNK_GROUP(1, 0)
    CHUNK_GROUP(1, 1)
    CHUNK_GROUP(2, 0)
    CHUNK_GROUP(2, 1)
#pragma unroll
    for (int ch = 0; ch < 2; ++ch) {
      const bf16x8 b = *(const bf16x8*)(bbase + (size_t)(96 + ch)*1024);
      const char* ap = pbase + q*VSTRIDE + 48*ROWB + ch*32 + hi*16;
      bf16x8 a0 = *(const bf16x8*)ap;
      bf16x8 a1 = *(const bf16x8*)(ap + 2*VSTRIDE);
      acc0 = __builtin_amdgcn_mfma_f32_32x32x16_bf16(a0, b, acc0, 0, 0, 0);
      acc1 = __builtin_amdgcn_mfma_f32_32x32x16_bf16(a1, b, acc1, 0, 0, 0);
    }

    // ---- Phase E: epilogue (max over d, +bias, relu, store) for current group ----
    // C/D layout (m74/m101): n = lane&31, m = (reg&3)+8*(reg>>2)+4*(lane>>5).
    {
      float m0 = acc0[0], m1 = acc0[8];
#pragma unroll
      for (int k = 1; k < 8; ++k) { m0 = fmaxf(m0, acc0[k]); m1 = fmaxf(m1, acc0[8+k]); }
      m0 = fmaxf(m0, __shfl_xor(m0, 32, 64));
      m1 = fmaxf(m1, __shfl_xor(m1, 32, 64));
      float v = (hi ? m1 : m0) + biasv;
      out[(size_t)(g*4 + hi)*64 + fh*32 + (l & 31)] = fmaxf(v, 0.f);
    }
    {
      float m0 = acc1[0], m1 = acc1[8];
#pragma unroll
      for (int k = 1; k < 8; ++k) { m0 = fmaxf(m0, acc1[k]); m1 = fmaxf(m1, acc1[8+k]); }
      m0 = fmaxf(m0, __shfl_xor(m0, 32, 64));
      m1 = fmaxf(m1, __shfl_xor(m1, 32, 64));
      float v = (hi ? m1 : m0) + biasv;
      out[(size_t)(g*4 + 2 + hi)*64 + fh*32 + (l & 31)] = fmaxf(v, 0.f);
    }

    // ---- Phase F: pack + ds_write next group's patches (y latency now drained) ----
    if (vnext) {
#pragma unroll
      for (int it = 0; it < 24; ++it)
        *(uint2*)(pbase + (it & 3)*VSTRIDE + ((it >> 2)*8 + rsl)*ROWB + cp*8) = pack4(yv[it]);
      if (l < 32)
        *(uint2*)(pbase + rsl*VSTRIDE + 48*ROWB + cp*8) = pack4(yv[24]);
    }

    g = gn; valid = vnext;
  }
}

extern "C" void kernel_launch(void* const* d_in, const int* in_sizes, int n_in,
                              void* d_out, int out_size, void* d_ws, size_t ws_size,
                              hipStream_t stream) {
  const float* y     = (const float*)d_in[0];
  const int*   em    = (const int*)  d_in[1];
  const float* kern  = (const float*)d_in[2];
  const float* ckern = (const float*)d_in[3];
  const float* bias  = (const float*)d_in[4];
  float* out = (float*)d_out;
  unsigned short* bpack = (unsigned short*)d_ws;   // 200704 bytes used

  // opt in to >64KB dynamic LDS (host-side, graph-capture safe — verified rounds 1-3)
  hipFuncSetAttribute(reinterpret_cast<const void*>(conv_kernel),
                      hipFuncAttributeMaxDynamicSharedMemorySize, LDS_TOT);

  prepack_kernel<<<(2*BPACK_HALF_USHORT + 255)/256, 256, 0, stream>>>(kern, ckern, bpack);
  conv_kernel<<<256, 256, LDS_TOT, stream>>>(y, em, bias, bpack, out);
}

// Round 5
// 229.036 us; speedup vs baseline: 5.2469x; 1.0448x over previous
//
#include <hip/hip_runtime.h>
#include <hip/hip_bf16.h>
#include <stdint.h>

// Problem constants (B=2, NV=25000, C=32, NR=3, ND=16, F=64)
#define NVERT 25000      // vertices per batch
#define NPAIR 25000      // total vertex-pairs (B*NV/2)
#define NGRP  12500      // pair-groups of 2 pairs (4 vertices) per wave-iter

typedef __bf16  bf16x8 __attribute__((ext_vector_type(8)));
typedef float   f32x16 __attribute__((ext_vector_type(16)));

#define NCHUNK 98                       // 96 conv chunks (r,ch,j) + 2 center chunks
#define BPACK_HALF_USHORT (NCHUNK*512)  // ushorts per f-half fragment pack
#define LDS_B   (NCHUNK*1024)           // 100352 B of B-fragments in LDS
#define ROWB    80                      // patch row stride (32 bf16 + 16B pad -> 2-way banks, free)
#define VSTRIDE (49*ROWB)               // per-vertex patch (48 rows + 1 center row) = 3920
#define WSTRIDE (4*VSTRIDE)             // per wave: 4 vertices (2 pairs) = 15680
#define LDS_TOT (LDS_B + 4*WSTRIDE)     // 163072 <= 163840

__device__ __forceinline__ uint2 pack4(float4 v) {
  // v_cvt_pk_bf16_f32 path (rne)
  union { __hip_bfloat162 h; unsigned u; } a, b;
  a.h = __float22bfloat162_rn(float2{v.x, v.y});
  b.h = __float22bfloat162_rn(float2{v.z, v.w});
  return uint2{a.u, b.u};
}

__device__ __forceinline__ unsigned short f2bf(float f) {
  unsigned int u = __float_as_uint(f);
  u += 0x7FFFu + ((u >> 16) & 1u);   // round-to-nearest-even
  return (unsigned short)(u >> 16);
}

// lane-rotate within 16-lane rows (row_ror:15) — verified direction (R1+ pass)
__device__ __forceinline__ bf16x8 rot16(bf16x8 x) {
  union { bf16x8 v; int i[4]; } u;
  u.v = x;
#pragma unroll
  for (int k = 0; k < 4; ++k)
    u.i[k] = __builtin_amdgcn_update_dpp(0, u.i[k], 0x12F, 0xF, 0xF, true);
  return u.v;
}

// Pack kernel (3,16,32,64) + center_kernel (32,64) into MFMA B-fragment order, bf16.
// Layout: bpack[fh(2)][kc(98)][lane(64)][i(8)] ushort.
// kc = (r*2+ch)*16 + j for conv; kc = 96+ch for center. B[k][n]: n=lane&31, k=8*(lane>>5)+i, c=ch*16+k.
__global__ __launch_bounds__(256) void prepack_kernel(
    const float* __restrict__ kern, const float* __restrict__ ckern,
    unsigned short* __restrict__ bpack)
{
  int tid = blockIdx.x*256 + threadIdx.x;
  if (tid >= 2*BPACK_HALF_USHORT) return;
  int fh  = tid / BPACK_HALF_USHORT;
  int rem = tid - fh*BPACK_HALF_USHORT;
  int kc  = rem >> 9;
  int e   = rem & 511;
  int l   = e >> 3, i = e & 7;
  int f   = fh*32 + (l & 31);
  int kk  = ((l >> 5) << 3) + i;
  float v;
  if (kc < 96) {
    int r = kc >> 5, ch = (kc >> 4) & 1, j = kc & 15;
    int c = ch*16 + kk;
    v = kern[((r*16 + j)*32 + c)*64 + f];
  } else {
    int c = (kc - 96)*16 + kk;
    v = ckern[c*64 + f];
  }
  bpack[tid] = f2bf(v);
}

// One r-pass, both c-halves interleaved: 4 independent MFMA chains
// (acc00=pair0/ch0, acc01=pair0/ch1, acc10=pair1/ch0, acc11=pair1/ch1).
// B 2-deep reg-prefetched per stream; A rotated in-register over j.
#define PASS(rr)                                                               \
  {                                                                            \
    const int rbase = ((rr)*16 + d)*ROWB + hi*16;                              \
    bf16x8 a00 = *(const bf16x8*)(pv0 + rbase);                                \
    bf16x8 a01 = *(const bf16x8*)(pv0 + rbase + 32);                           \
    bf16x8 a10 = *(const bf16x8*)(pv1 + rbase);                                \
    bf16x8 a11 = *(const bf16x8*)(pv1 + rbase + 32);                           \
    const char* bp0 = bbase + (size_t)(((rr)*2 + 0)*16) * 1024;                \
    const char* bp1 = bbase + (size_t)(((rr)*2 + 1)*16) * 1024;                \
    bf16x8 b0a = *(const bf16x8*)bp0;                                          \
    bf16x8 b1a = *(const bf16x8*)bp1;                                          \
    bf16x8 b0b = *(const bf16x8*)(bp0 + 1024);                                 \
    bf16x8 b1b = *(const bf16x8*)(bp1 + 1024);                                 \
    _Pragma("unroll")                                                          \
    for (int j = 0; j < 16; ++j) {                                             \
      const bf16x8 b0 = b0a, b1 = b1a;                                         \
      b0a = b0b; b1a = b1b;                                                    \
      if (j < 14) {                                                            \
        b0b = *(const bf16x8*)(bp0 + (size_t)(j+2)*1024);                      \
        b1b = *(const bf16x8*)(bp1 + (size_t)(j+2)*1024);                      \
      }                                                                        \
      acc00 = __builtin_amdgcn_mfma_f32_32x32x16_bf16(a00, b0, acc00, 0,0,0);  \
      acc10 = __builtin_amdgcn_mfma_f32_32x32x16_bf16(a10, b0, acc10, 0,0,0);  \
      acc01 = __builtin_amdgcn_mfma_f32_32x32x16_bf16(a01, b1, acc01, 0,0,0);  \
      acc11 = __builtin_amdgcn_mfma_f32_32x32x16_bf16(a11, b1, acc11, 0,0,0);  \
      if (j < 15) {                                                            \
        a00 = rot16(a00); a01 = rot16(a01);                                    \
        a10 = rot16(a10); a11 = rot16(a11);                                    \
      }                                                                        \
    }                                                                          \
  }

__global__ __launch_bounds__(256, 1) void conv_kernel(
    const float* __restrict__ y,
    const int*   __restrict__ em,     // exp_map int pairs (b,v), flat (u*48 + r*16+dd)
    const float* __restrict__ bias,
    const unsigned short* __restrict__ bpack,
    float* __restrict__ out)
{
  extern __shared__ __align__(16) char smem[];
  const int fh  = blockIdx.x & 1;     // which 32-wide f half
  const int bl  = blockIdx.x >> 1;    // 0..127
  const int tid = threadIdx.x;
  const int w   = tid >> 6;           // wave 0..3
  const int l   = tid & 63;

  // ---- stage this f-half's B fragments into LDS (once per block) ----
  {
    const uint4* src = (const uint4*)(bpack + (size_t)fh * BPACK_HALF_USHORT);
    uint4* dst = (uint4*)smem;
    for (int idx = tid; idx < LDS_B/16; idx += 256) dst[idx] = src[idx];
  }
  __syncthreads();
  // No barriers after this; per-wave DS ordering protects the private patch buffer.

  char* pbase = smem + LDS_B + w * WSTRIDE;
  const char* bbase = smem + (size_t)l * 16;    // canonical fragment read: 0 conflicts (R3 PMC)
  const float biasv = bias[fh*32 + (l & 31)];
  const int gw = bl*4 + w;            // global wave id within f-half, 0..511
  const int q  = (l >> 4) & 1;        // A-operand: which vertex of the pair (m>>4)
  const int d  = l & 15;              // A-operand: direction (m&15)
  const int hi = l >> 5;              // A/B operand: k-half selector
  const char* pv0 = pbase + q*VSTRIDE;              // pair 0, this lane's vertex
  const char* pv1 = pbase + (2 + q)*VSTRIDE;        // pair 1
  const int2* em2 = (const int2*)em;
  // staging lane roles: row-slot = l>>3 (8 rows/step), c-quarter = l&7
  const int rsl = l >> 3, cp = l & 7;

  int g = gw;
  bool valid = (g < NGRP);

  // ---- prologue: stage group g fully (latency exposed once) ----
  if (valid) {
    int2 e0[24];
#pragma unroll
    for (int it = 0; it < 24; ++it)
      e0[it] = em2[(g*4 + (it & 3))*48 + (it >> 2)*8 + rsl];
    float4 yv0[25];
#pragma unroll
    for (int it = 0; it < 24; ++it)
      yv0[it] = *(const float4*)(y + ((size_t)e0[it].x*NVERT + (size_t)e0[it].y)*32 + cp*4);
    yv0[24] = *(const float4*)(y + (size_t)(g*4 + (rsl & 3))*32 + cp*4);
#pragma unroll
    for (int it = 0; it < 24; ++it)
      *(uint2*)(pbase + (it & 3)*VSTRIDE + ((it >> 2)*8 + rsl)*ROWB + cp*8) = pack4(yv0[it]);
    if (l < 32)
      *(uint2*)(pbase + rsl*VSTRIDE + 48*ROWB + cp*8) = pack4(yv0[24]);
  }

  for (int t = 0; t < 25; ++t) {
    if (!valid) break;
    const int gn = g + 512;
    const bool vnext = (gn < NGRP);

    // ---- Phase A: issue next group's em loads (latency hidden by r=0 compute) ----
    int2 e[24];
    if (vnext) {
#pragma unroll
      for (int it = 0; it < 24; ++it)
        e[it] = em2[(gn*4 + (it & 3))*48 + (it >> 2)*8 + rsl];
    }

    f32x16 acc00, acc01, acc10, acc11;
#pragma unroll
    for (int k = 0; k < 16; ++k) {
      acc00[k] = 0.f; acc01[k] = 0.f; acc10[k] = 0.f; acc11[k] = 0.f;
    }

    // ---- Phase B: r=0 (2048 cyc of MFMA pipe covers em latency) ----
    PASS(0)

    // ---- Phase C: issue next group's y gathers (latency hidden by r=1,2) ----
    float4 yv[25];
    if (vnext) {
#pragma unroll
      for (int it = 0; it < 24; ++it)
        yv[it] = *(const float4*)(y + ((size_t)e[it].x*NVERT + (size_t)e[it].y)*32 + cp*4);
      yv[24] = *(const float4*)(y + (size_t)(gn*4 + (rsl & 3))*32 + cp*4);
    }

    // ---- Phase D: r=1, r=2, center ----
    PASS(1)
    PASS(2)
    {
      const bf16x8 bc0 = *(const bf16x8*)(bbase + (size_t)96*1024);
      const bf16x8 bc1 = *(const bf16x8*)(bbase + (size_t)97*1024);
      const char* c0 = pv0 + 48*ROWB + hi*16;
      const char* c1 = pv1 + 48*ROWB + hi*16;
      bf16x8 a00 = *(const bf16x8*)c0;
      bf16x8 a01 = *(const bf16x8*)(c0 + 32);
      bf16x8 a10 = *(const bf16x8*)c1;
      bf16x8 a11 = *(const bf16x8*)(c1 + 32);
      acc00 = __builtin_amdgcn_mfma_f32_32x32x16_bf16(a00, bc0, acc00, 0,0,0);
      acc10 = __builtin_amdgcn_mfma_f32_32x32x16_bf16(a10, bc0, acc10, 0,0,0);
      acc01 = __builtin_amdgcn_mfma_f32_32x32x16_bf16(a01, bc1, acc01, 0,0,0);
      acc11 = __builtin_amdgcn_mfma_f32_32x32x16_bf16(a11, bc1, acc11, 0,0,0);
    }

    // ---- Phase E: epilogue — sum c-halves, max over d, +bias, relu, store ----
    // C/D layout (m74/m101): n = lane&31, m = (reg&3)+8*(reg>>2)+4*(lane>>5).
    {
      float m0 = acc00[0] + acc01[0], m1 = acc00[8] + acc01[8];
#pragma unroll
      for (int k = 1; k < 8; ++k) {
        m0 = fmaxf(m0, acc00[k]   + acc01[k]);
        m1 = fmaxf(m1, acc00[8+k] + acc01[8+k]);
      }
      m0 = fmaxf(m0, __shfl_xor(m0, 32, 64));
      m1 = fmaxf(m1, __shfl_xor(m1, 32, 64));
      float v = (hi ? m1 : m0) + biasv;
      out[(size_t)(g*4 + hi)*64 + fh*32 + (l & 31)] = fmaxf(v, 0.f);
    }
    {
      float m0 = acc10[0] + acc11[0], m1 = acc10[8] + acc11[8];
#pragma unroll
      for (int k = 1; k < 8; ++k) {
        m0 = fmaxf(m0, acc10[k]   + acc11[k]);
        m1 = fmaxf(m1, acc10[8+k] + acc11[8+k]);
      }
      m0 = fmaxf(m0, __shfl_xor(m0, 32, 64));
      m1 = fmaxf(m1, __shfl_xor(m1, 32, 64));
      float v = (hi ? m1 : m0) + biasv;
      out[(size_t)(g*4 + 2 + hi)*64 + fh*32 + (l & 31)] = fmaxf(v, 0.f);
    }

    // ---- Phase F: pack + ds_write next group's patches (y latency now drained) ----
    if (vnext) {
#pragma unroll
      for (int it = 0; it < 24; ++it)
        *(uint2*)(pbase + (it & 3)*VSTRIDE + ((it >> 2)*8 + rsl)*ROWB + cp*8) = pack4(yv[it]);
      if (l < 32)
        *(uint2*)(pbase + rsl*VSTRIDE + 48*ROWB + cp*8) = pack4(yv[24]);
    }

    g = gn; valid = vnext;
  }
}

extern "C" void kernel_launch(void* const* d_in, const int* in_sizes, int n_in,
                              void* d_out, int out_size, void* d_ws, size_t ws_size,
                              hipStream_t stream) {
  const float* y     = (const float*)d_in[0];
  const int*   em    = (const int*)  d_in[1];
  const float* kern  = (const float*)d_in[2];
  const float* ckern = (const float*)d_in[3];
  const float* bias  = (const float*)d_in[4];
  float* out = (float*)d_out;
  unsigned short* bpack = (unsigned short*)d_ws;   // 200704 bytes used

  // opt in to >64KB dynamic LDS (host-side, graph-capture safe — verified rounds 1-4)
  hipFuncSetAttribute(reinterpret_cast<const void*>(conv_kernel),
                      hipFuncAttributeMaxDynamicSharedMemorySize, LDS_TOT);

  prepack_kernel<<<(2*BPACK_HALF_USHORT + 255)/256, 256, 0, stream>>>(kern, ckern, bpack);
  conv_kernel<<<256, 256, LDS_TOT, stream>>>(y, em, bias, bpack, out);
}